// Round 4
// baseline (2718.389 us; speedup 1.0000x reference)
//
#include <hip/hip_runtime.h>

#define N 307
#define NP 320
#define CIN 5
#define HID 16
#define KORD 6
#define LH 32
#define BATCH 512
#define NT 320

#define DTS 328   // u16 stride per h-row of D^T (656 B, multiple of 16)
#define O1S 20    // float stride of o1buf rows (80 B, 16-aligned)

typedef _Float16 half8 __attribute__((ext_vector_type(8)));
typedef float f32x4 __attribute__((ext_vector_type(4)));

__device__ __forceinline__ float sigmoidf(float x) {
    return __fdividef(1.f, 1.f + __expf(-x));
}
__device__ __forceinline__ float ftanh(float x) {
    float e = __expf(2.f * x);
    return 1.f - __fdividef(2.f, e + 1.f);
}

// ---------------- graph setup ----------------
__global__ __launch_bounds__(NT) void k_cosine(const float* __restrict__ E,
                                               float* __restrict__ G,
                                               float* __restrict__ dinv) {
    __shared__ float Es[N * 10];
    __shared__ float ninv[N];
    __shared__ float red[NT / 64];
    const int n = blockIdx.x, t = threadIdx.x;
    for (int i = t; i < N * 10; i += NT) Es[i] = E[i];
    __syncthreads();
    for (int r = t; r < N; r += NT) {
        float s = 0.f;
        for (int j = 0; j < 10; j++) { float v = Es[r * 10 + j]; s += v * v; }
        ninv[r] = rsqrtf(s);
    }
    __syncthreads();
    float gval = 0.f;
    if (t < N) {
        float s = 0.f;
        for (int j = 0; j < 10; j++) s += Es[n * 10 + j] * Es[t * 10 + j];
        gval = s * ninv[n] * ninv[t];
        G[n * N + t] = gval;
    }
    float v = gval;
    for (int off = 32; off; off >>= 1) v += __shfl_down(v, off);
    if ((t & 63) == 0) red[t >> 6] = v;
    __syncthreads();
    if (t == 0) {
        float s = 0.f;
        for (int w = 0; w < NT / 64; w++) s += red[w];
        dinv[n] = rsqrtf(s);
    }
}

__global__ __launch_bounds__(NT) void k_laplacian(const float* __restrict__ G,
                                                  const float* __restrict__ dinv,
                                                  float* __restrict__ polys) {
    const int n = blockIdx.x, t = threadIdx.x;
    if (t < N) {
        float eye = (t == n) ? 1.f : 0.f;
        float l = eye - dinv[n] * G[n * N + t] * dinv[t];
        polys[0 * N * N + n * N + t] = eye;
        polys[1 * N * N + n * N + t] = l;
    }
}

__global__ __launch_bounds__(NT) void k_cheb_step(float* __restrict__ polys, int k) {
    __shared__ float Lrow[N];
    const int n = blockIdx.x, t = threadIdx.x;
    const float* L = polys + 1 * N * N;
    for (int i = t; i < N; i += NT) Lrow[i] = L[n * N + i];
    __syncthreads();
    if (t < N) {
        const float* Tprev = polys + (size_t)(k - 1) * N * N;
        float acc = -polys[(size_t)(k - 2) * N * N + n * N + t];
        for (int m = 0; m < N; m++) acc = fmaf(2.f * Lrow[m], Tprev[m * N + t], acc);
        polys[(size_t)k * N * N + n * N + t] = acc;
    }
}

// ---------------- prep: L -> fp16 hi/lo A-fragments (MFMA 16x16x32 layout) ----
// Afrag[tile(20)][kstep(10)][lane(64)][j(8)], value = L[tile*16+(lane&15)][kstep*32+(lane>>4)*8+j]
__global__ __launch_bounds__(256) void k_prepA(const float* __restrict__ polys,
                                               _Float16* __restrict__ Ahi,
                                               _Float16* __restrict__ Alo) {
    const int idx = blockIdx.x * 256 + threadIdx.x;  // frag id: 20*10*64 = 12800
    if (idx >= 20 * 10 * 64) return;
    const int ln = idx & 63;
    const int ks = (idx >> 6) % 10;
    const int tl = (idx >> 6) / 10;
    const int m = tl * 16 + (ln & 15);
    const int k0 = ks * 32 + (ln >> 4) * 8;
    const float* L = polys + N * N;
    #pragma unroll
    for (int j = 0; j < 8; j++) {
        int k = k0 + j;
        float v = (m < N && k < N) ? L[(size_t)m * N + k] : 0.f;
        _Float16 h = (_Float16)v;
        float lof = v - (float)h;
        Ahi[(size_t)idx * 8 + j] = h;
        Alo[(size_t)idx * 8 + j] = (_Float16)lof;
    }
}

// ---------------- NL evaluation (device fn) ----------------
__device__ __forceinline__ void nl_eval(const float x[HID],
                                        const float* __restrict__ WiT,
                                        const float* __restrict__ WgT,
                                        const float* __restrict__ WoT,
                                        const float* __restrict__ w2S,
                                        const float* __restrict__ bS,
                                        float outv[HID]) {
    #pragma unroll
    for (int h = 0; h < HID; h++) outv[h] = 0.f;
    for (int j = 0; j < LH; j++) {
        float gi = bS[j], gg = bS[2 * LH + j], go = bS[3 * LH + j];
        const float4* wi = (const float4*)(WiT + j * HID);
        const float4* wg = (const float4*)(WgT + j * HID);
        const float4* wo4 = (const float4*)(WoT + j * HID);
        #pragma unroll
        for (int q = 0; q < 4; q++) {
            float4 a = wi[q], bb = wg[q], cc = wo4[q];
            gi = fmaf(x[4*q+0], a.x, gi); gi = fmaf(x[4*q+1], a.y, gi);
            gi = fmaf(x[4*q+2], a.z, gi); gi = fmaf(x[4*q+3], a.w, gi);
            gg = fmaf(x[4*q+0], bb.x, gg); gg = fmaf(x[4*q+1], bb.y, gg);
            gg = fmaf(x[4*q+2], bb.z, gg); gg = fmaf(x[4*q+3], bb.w, gg);
            go = fmaf(x[4*q+0], cc.x, go); go = fmaf(x[4*q+1], cc.y, go);
            go = fmaf(x[4*q+2], cc.z, go); go = fmaf(x[4*q+3], cc.w, go);
        }
        float c = sigmoidf(gi) * ftanh(gg);
        float hh = sigmoidf(go) * ftanh(c);
        float th = ftanh(hh);
        const float4* w2r = (const float4*)(w2S + j * HID);
        #pragma unroll
        for (int q = 0; q < 4; q++) {
            float4 a = w2r[q];
            outv[4*q+0] = fmaf(th, a.x, outv[4*q+0]);
            outv[4*q+1] = fmaf(th, a.y, outv[4*q+1]);
            outv[4*q+2] = fmaf(th, a.z, outv[4*q+2]);
            outv[4*q+3] = fmaf(th, a.w, outv[4*q+3]);
        }
    }
}

// ---------------- GL via MFMA (wave-cooperative; call from ALL 320 threads) ---
__device__ __forceinline__ void gl_eval_mfma(
    const float vin[HID], int t,
    const _Float16* __restrict__ AhiG, const _Float16* __restrict__ AloG,
    _Float16* DT, float* o1buf,
    const float* __restrict__ woS, const float* __restrict__ wfS,
    const float* __restrict__ wtS, const float* __restrict__ btS,
    float z[HID]) {
    // barrier: previous eval's DT readers must finish before overwrite
    __syncthreads();
    // phase A: split-write D^T (zero for pad rows)
    const bool valid = (t < N);
    #pragma unroll
    for (int h = 0; h < HID; h++) {
        float f = valid ? vin[h] : 0.f;
        _Float16 hi = (_Float16)f;
        float lof = f - (float)hi;
        DT[h * DTS + t] = hi;
        DT[(16 + h) * DTS + t] = (_Float16)lof;
    }
    __syncthreads();
    // phase B: o1 = L @ D via 3-term fp16-split MFMA
    const int ln = t & 63, wv = t >> 6;
    const int hb = ln & 15, gb = ln >> 4;
    f32x4 acc0 = {0.f, 0.f, 0.f, 0.f}, acc1 = acc0, acc2 = acc0, acc3 = acc0;
    const half8* Ah8 = (const half8*)AhiG;
    const half8* Al8 = (const half8*)AloG;
    #pragma unroll 2
    for (int kk = 0; kk < 10; kk++) {
        half8 Bh = *(const half8*)&DT[hb * DTS + kk * 32 + gb * 8];
        half8 Bl = *(const half8*)&DT[(16 + hb) * DTS + kk * 32 + gb * 8];
        const int base = ((wv * 4) * 10 + kk) * 64 + ln;
        half8 a0h = Ah8[base],            a0l = Al8[base];
        half8 a1h = Ah8[base + 10 * 64],  a1l = Al8[base + 10 * 64];
        half8 a2h = Ah8[base + 20 * 64],  a2l = Al8[base + 20 * 64];
        half8 a3h = Ah8[base + 30 * 64],  a3l = Al8[base + 30 * 64];
        acc0 = __builtin_amdgcn_mfma_f32_16x16x32_f16(a0h, Bh, acc0, 0, 0, 0);
        acc1 = __builtin_amdgcn_mfma_f32_16x16x32_f16(a1h, Bh, acc1, 0, 0, 0);
        acc2 = __builtin_amdgcn_mfma_f32_16x16x32_f16(a2h, Bh, acc2, 0, 0, 0);
        acc3 = __builtin_amdgcn_mfma_f32_16x16x32_f16(a3h, Bh, acc3, 0, 0, 0);
        acc0 = __builtin_amdgcn_mfma_f32_16x16x32_f16(a0h, Bl, acc0, 0, 0, 0);
        acc1 = __builtin_amdgcn_mfma_f32_16x16x32_f16(a1h, Bl, acc1, 0, 0, 0);
        acc2 = __builtin_amdgcn_mfma_f32_16x16x32_f16(a2h, Bl, acc2, 0, 0, 0);
        acc3 = __builtin_amdgcn_mfma_f32_16x16x32_f16(a3h, Bl, acc3, 0, 0, 0);
        acc0 = __builtin_amdgcn_mfma_f32_16x16x32_f16(a0l, Bh, acc0, 0, 0, 0);
        acc1 = __builtin_amdgcn_mfma_f32_16x16x32_f16(a1l, Bh, acc1, 0, 0, 0);
        acc2 = __builtin_amdgcn_mfma_f32_16x16x32_f16(a2l, Bh, acc2, 0, 0, 0);
        acc3 = __builtin_amdgcn_mfma_f32_16x16x32_f16(a3l, Bh, acc3, 0, 0, 0);
    }
    // scatter C-frags: row = wv*64 + t4*16 + gb*4 + q, col = hb (wave-local rows)
    #pragma unroll
    for (int q = 0; q < 4; q++) {
        o1buf[(wv * 64 +  0 + gb * 4 + q) * O1S + hb] = acc0[q];
        o1buf[(wv * 64 + 16 + gb * 4 + q) * O1S + hb] = acc1[q];
        o1buf[(wv * 64 + 32 + gb * 4 + q) * O1S + hb] = acc2[q];
        o1buf[(wv * 64 + 48 + gb * 4 + q) * O1S + hb] = acc3[q];
    }
    // gather own row (same wave wrote it; DS ops are in-order per wave)
    float o1[HID];
    {
        const float4* gr = (const float4*)&o1buf[t * O1S];
        float4 r0 = gr[0], r1 = gr[1], r2 = gr[2], r3 = gr[3];
        o1[0]=r0.x; o1[1]=r0.y; o1[2]=r0.z; o1[3]=r0.w;
        o1[4]=r1.x; o1[5]=r1.y; o1[6]=r1.z; o1[7]=r1.w;
        o1[8]=r2.x; o1[9]=r2.y; o1[10]=r2.z; o1[11]=r2.w;
        o1[12]=r3.x; o1[13]=r3.y; o1[14]=r3.z; o1[15]=r3.w;
    }
    // phase C: o3 = tanh(tanh(x@wo)@wf); z = (o1 - o3)@wt + bt
    float y[HID] = {};
    #pragma unroll
    for (int h2 = 0; h2 < HID; h2++) {
        float xv = vin[h2];
        #pragma unroll
        for (int h = 0; h < HID; h++) y[h] = fmaf(xv, woS[h2 * HID + h], y[h]);
    }
    #pragma unroll
    for (int h = 0; h < HID; h++) y[h] = ftanh(y[h]);
    float y2[HID] = {};
    #pragma unroll
    for (int h2 = 0; h2 < HID; h2++) {
        float xv = y[h2];
        #pragma unroll
        for (int h = 0; h < HID; h++) y2[h] = fmaf(xv, wfS[h2 * HID + h], y2[h]);
    }
    #pragma unroll
    for (int h = 0; h < HID; h++) z[h] = btS[h];
    #pragma unroll
    for (int h2 = 0; h2 < HID; h2++) {
        float v = o1[h2] - ftanh(y2[h2]);
        #pragma unroll
        for (int h = 0; h < HID; h++) z[h] = fmaf(v, wtS[h2 * HID + h], z[h]);
    }
}

// ---------------- fused chain: init + 10x GL (MFMA) + cstep + 10x NL ----------
__global__ __launch_bounds__(NT, 3) void k_chain(
    const float* __restrict__ flow,
    const float* __restrict__ polys,
    const _Float16* __restrict__ AhiG, const _Float16* __restrict__ AloG,
    const float* __restrict__ cheb_w, const float* __restrict__ cheb_b,
    const float* __restrict__ cou_w,
    const float* __restrict__ gl_wo, const float* __restrict__ gl_wf,
    const float* __restrict__ gl_wt, const float* __restrict__ gl_bt,
    const float* __restrict__ Wih, const float* __restrict__ bih,
    const float* __restrict__ w2,
    const float* __restrict__ c_w, const float* __restrict__ c_b,
    const float* __restrict__ c1_w, const float* __restrict__ c1_b,
    float* __restrict__ out) {
    __shared__ _Float16 DT[2 * 16 * DTS];
    __shared__ float o1buf[NP * O1S];
    __shared__ float woS[256], wfS[256], wtS[256], btS[16];
    __shared__ float cwS[256], c1wS[256], cbS[16], c1bS[16];
    __shared__ float WiT[LH * HID], WgT[LH * HID], WoT[LH * HID], w2S[LH * HID], bS[4 * LH];
    __shared__ float chebS[KORD * CIN * HID], chebBS[16], couS[CIN * HID];

    const int t = threadIdx.x;
    const int n = t;
    const int b = blockIdx.x;

    for (int i = t; i < 256; i += NT) {
        woS[i] = gl_wo[i]; wfS[i] = gl_wf[i]; wtS[i] = gl_wt[i];
        cwS[i] = c_w[i]; c1wS[i] = c1_w[i];
    }
    for (int i = t; i < LH * HID; i += NT) {
        int j = i >> 4, h = i & 15;
        WiT[i] = Wih[h * 4 * LH + j];
        WgT[i] = Wih[h * 4 * LH + 2 * LH + j];
        WoT[i] = Wih[h * 4 * LH + 3 * LH + j];
        w2S[i] = w2[i];
    }
    for (int i = t; i < 4 * LH; i += NT) bS[i] = bih[i];
    for (int i = t; i < KORD * CIN * HID; i += NT) chebS[i] = cheb_w[i];
    for (int i = t; i < HID; i += NT) {
        btS[i] = gl_bt[i]; cbS[i] = c_b[i]; c1bS[i] = c1_b[i]; chebBS[i] = cheb_b[i];
    }
    for (int i = t; i < CIN * HID; i += NT) couS[i] = cou_w[i];
    // stage x into o1buf region (reused later), stride 8
    float* xs = o1buf;
    for (int i = t; i < N * CIN; i += NT) {
        int nn = i / CIN, c = i - nn * CIN;
        xs[nn * 8 + c] = flow[(size_t)b * N * CIN + i];
    }
    __syncthreads();

    float prev2[HID] = {}, cur[HID] = {};
    // ---- init: prev2 = x@cou_w ; cur = cheb output ----
    if (n < N) {
        float xv[CIN];
        #pragma unroll
        for (int c = 0; c < CIN; c++) xv[c] = xs[n * 8 + c];
        #pragma unroll
        for (int h = 0; h < HID; h++) {
            float s = 0.f;
            #pragma unroll
            for (int c = 0; c < CIN; c++) s = fmaf(xv[c], couS[c * HID + h], s);
            prev2[h] = s;
            cur[h] = chebBS[h];
        }
        for (int k = 0; k < KORD; k++) {
            const float* P = polys + (size_t)k * N * N + n;  // symmetric: col n == row n
            float hk[CIN] = {};
            #pragma unroll 4
            for (int m = 0; m < N; m++) {
                float p = P[(size_t)m * N];
                #pragma unroll
                for (int c = 0; c < CIN; c++) hk[c] = fmaf(p, xs[m * 8 + c], hk[c]);
            }
            #pragma unroll
            for (int c = 0; c < CIN; c++) {
                float hv = hk[c];
                #pragma unroll
                for (int h = 0; h < HID; h++)
                    cur[h] = fmaf(hv, chebS[(k * CIN + c) * HID + h], cur[h]);
            }
        }
    }

    // ---- GL chain (each eval begins with its own barrier) ----
    for (int it = 0; it < 10; it++) {
        float tt[HID], uu[HID], tmp[HID];
        gl_eval_mfma(cur, t, AhiG, AloG, DT, o1buf, woS, wfS, wtS, btS, tt);
        #pragma unroll
        for (int h = 0; h < HID; h++) tmp[h] = fmaf(2.f, tt[h], prev2[h]);
        gl_eval_mfma(tmp, t, AhiG, AloG, DT, o1buf, woS, wfS, wtS, btS, uu);
        #pragma unroll
        for (int h = 0; h < HID; h++) {
            float nc = cur[h] + 0.5f * (tt[h] + uu[h]);
            prev2[h] = cur[h];
            cur[h] = nc;
        }
    }

    // ---- cstep + NL chain (pointwise; no barriers) ----
    if (n < N) {
        float s00[HID], s11[HID];
        #pragma unroll
        for (int h = 0; h < HID; h++) { s00[h] = cbS[h]; s11[h] = c1bS[h]; }
        #pragma unroll
        for (int h2 = 0; h2 < HID; h2++) {
            float a = prev2[h2], c2 = cur[h2];
            #pragma unroll
            for (int h = 0; h < HID; h++) {
                s00[h] = fmaf(a, cwS[h2 * HID + h], s00[h]);
                s11[h] = fmaf(c2, c1wS[h2 * HID + h], s11[h]);
            }
        }
        float* obase = out + ((size_t)b * N + n) * 10 * HID;
        float tt[HID], uu[HID], g[HID], p2[HID];
        nl_eval(s11, WiT, WgT, WoT, w2S, bS, tt);
        #pragma unroll
        for (int h = 0; h < HID; h++) s00[h] = fmaf(2.f, tt[h], s00[h]);
        nl_eval(s00, WiT, WgT, WoT, w2S, bS, uu);
        #pragma unroll
        for (int h = 0; h < HID; h++) {
            g[h] = cur[h] + 0.5f * (tt[h] + uu[h]);
            p2[h] = s11[h];
        }
        {
            float4* w = (float4*)obase;
            w[0] = make_float4(g[0], g[1], g[2], g[3]);
            w[1] = make_float4(g[4], g[5], g[6], g[7]);
            w[2] = make_float4(g[8], g[9], g[10], g[11]);
            w[3] = make_float4(g[12], g[13], g[14], g[15]);
        }
        for (int i = 1; i < 10; i++) {
            nl_eval(g, WiT, WgT, WoT, w2S, bS, tt);
            #pragma unroll
            for (int h = 0; h < HID; h++) p2[h] = fmaf(2.f, tt[h], p2[h]);
            nl_eval(p2, WiT, WgT, WoT, w2S, bS, uu);
            #pragma unroll
            for (int h = 0; h < HID; h++) {
                float ng = g[h] + 0.5f * (tt[h] + uu[h]);
                p2[h] = g[h];
                g[h] = ng;
            }
            float4* w = (float4*)(obase + i * HID);
            w[0] = make_float4(g[0], g[1], g[2], g[3]);
            w[1] = make_float4(g[4], g[5], g[6], g[7]);
            w[2] = make_float4(g[8], g[9], g[10], g[11]);
            w[3] = make_float4(g[12], g[13], g[14], g[15]);
        }
    }
}

extern "C" void kernel_launch(void* const* d_in, const int* in_sizes, int n_in,
                              void* d_out, int out_size, void* d_ws, size_t ws_size,
                              hipStream_t stream) {
    const float* flow   = (const float*)d_in[0];
    const float* emb    = (const float*)d_in[1];
    const float* cheb_w = (const float*)d_in[2];
    const float* cheb_b = (const float*)d_in[3];
    const float* cou_w  = (const float*)d_in[4];
    const float* gl_out = (const float*)d_in[5];
    const float* gl_fk  = (const float*)d_in[6];
    const float* gl_tzw = (const float*)d_in[7];
    const float* gl_tzb = (const float*)d_in[8];
    const float* Wih    = (const float*)d_in[9];
    const float* lb     = (const float*)d_in[10];
    const float* w2     = (const float*)d_in[11];
    const float* c_w    = (const float*)d_in[12];
    const float* c_b    = (const float*)d_in[13];
    const float* c1_w   = (const float*)d_in[14];
    const float* c1_b   = (const float*)d_in[15];
    float* out = (float*)d_out;
    float* ws  = (float*)d_ws;

    size_t off = 0;
    float* polys = ws;       off += (size_t)KORD * N * N; off = (off + 255) & ~(size_t)255;
    float* G     = ws + off; off += (size_t)N * N;        off = (off + 255) & ~(size_t)255;
    float* dinv  = ws + off; off += 512;
    _Float16* Ahi = (_Float16*)(ws + off); off += (20 * 10 * 64 * 8) / 2;  // 51200 floats
    _Float16* Alo = (_Float16*)(ws + off); off += (20 * 10 * 64 * 8) / 2;

    k_cosine<<<N, NT, 0, stream>>>(emb, G, dinv);
    k_laplacian<<<N, NT, 0, stream>>>(G, dinv, polys);
    for (int k = 2; k < KORD; k++)
        k_cheb_step<<<N, NT, 0, stream>>>(polys, k);
    k_prepA<<<(20 * 10 * 64 + 255) / 256, 256, 0, stream>>>(polys, Ahi, Alo);
    k_chain<<<BATCH, NT, 0, stream>>>(flow, polys, Ahi, Alo, cheb_w, cheb_b, cou_w,
                                      gl_out, gl_fk, gl_tzw, gl_tzb,
                                      Wih, lb, w2, c_w, c_b, c1_w, c1_b, out);
}

// Round 5
// 2429.590 us; speedup vs baseline: 1.1189x; 1.1189x over previous
//
#include <hip/hip_runtime.h>

#define N 307
#define CIN 5
#define HID 16
#define KORD 6
#define LH 32
#define BATCH 512
#define NT 320

typedef float f32x16 __attribute__((ext_vector_type(16)));

__device__ __forceinline__ float sigmoidf(float x) {
    return __fdividef(1.f, 1.f + __expf(-x));
}
__device__ __forceinline__ float ftanh(float x) {
    float e = __expf(2.f * x);
    return 1.f - __fdividef(2.f, e + 1.f);
}
__device__ __forceinline__ f32x16 ldsrow(const float* __restrict__ p) {
    return *(const f32x16*)p;
}

// ---------------- graph setup ----------------
__global__ __launch_bounds__(NT) void k_cosine(const float* __restrict__ E,
                                               float* __restrict__ G,
                                               float* __restrict__ dinv) {
    __shared__ float Es[N * 10];
    __shared__ float ninv[N];
    __shared__ float red[NT / 64];
    const int n = blockIdx.x, t = threadIdx.x;
    for (int i = t; i < N * 10; i += NT) Es[i] = E[i];
    __syncthreads();
    for (int r = t; r < N; r += NT) {
        float s = 0.f;
        for (int j = 0; j < 10; j++) { float v = Es[r * 10 + j]; s += v * v; }
        ninv[r] = rsqrtf(s);
    }
    __syncthreads();
    float gval = 0.f;
    if (t < N) {
        float s = 0.f;
        for (int j = 0; j < 10; j++) s += Es[n * 10 + j] * Es[t * 10 + j];
        gval = s * ninv[n] * ninv[t];
        G[n * N + t] = gval;
    }
    float v = gval;
    for (int off = 32; off; off >>= 1) v += __shfl_down(v, off);
    if ((t & 63) == 0) red[t >> 6] = v;
    __syncthreads();
    if (t == 0) {
        float s = 0.f;
        for (int w = 0; w < NT / 64; w++) s += red[w];
        dinv[n] = rsqrtf(s);
    }
}

__global__ __launch_bounds__(NT) void k_laplacian(const float* __restrict__ G,
                                                  const float* __restrict__ dinv,
                                                  float* __restrict__ polys) {
    const int n = blockIdx.x, t = threadIdx.x;
    if (t < N) {
        float eye = (t == n) ? 1.f : 0.f;
        float l = eye - dinv[n] * G[n * N + t] * dinv[t];
        polys[0 * N * N + n * N + t] = eye;
        polys[1 * N * N + n * N + t] = l;
    }
}

__global__ __launch_bounds__(NT) void k_cheb_step(float* __restrict__ polys, int k) {
    __shared__ float Lrow[N];
    const int n = blockIdx.x, t = threadIdx.x;
    const float* L = polys + 1 * N * N;
    for (int i = t; i < N; i += NT) Lrow[i] = L[n * N + i];
    __syncthreads();
    if (t < N) {
        const float* Tprev = polys + (size_t)(k - 1) * N * N;
        float acc = -polys[(size_t)(k - 2) * N * N + n * N + t];
        for (int m = 0; m < N; m++) acc = fmaf(2.f * Lrow[m], Tprev[m * N + t], acc);
        polys[(size_t)k * N * N + n * N + t] = acc;
    }
}

// ---------------- GL eval: z = (L@D - tanh(tanh(x@wo)@wf)) @ wt + bt ----------
// Lcol = L + n (symmetric L: column n == row n; lane-coalesced at fixed m).
// D rows live in LDS buf (stride 16, 64B-aligned). All state in by-value vectors.
__device__ __forceinline__ f32x16 gl_eval(const float* __restrict__ Lcol,
                                          const float* __restrict__ buf,
                                          f32x16 x,
                                          const float* __restrict__ woS,
                                          const float* __restrict__ wfS,
                                          const float* __restrict__ wtS,
                                          const float* __restrict__ btS) {
    f32x16 o1 = 0.f;
    #pragma unroll 4
    for (int m = 0; m < N; m++) {
        float lv = Lcol[(size_t)m * N];
        o1 += lv * ldsrow(buf + m * HID);
    }
    f32x16 y = 0.f;
    #pragma unroll
    for (int h2 = 0; h2 < HID; h2++) y += x[h2] * ldsrow(woS + h2 * HID);
    #pragma unroll
    for (int h = 0; h < HID; h++) y[h] = ftanh(y[h]);
    f32x16 y2 = 0.f;
    #pragma unroll
    for (int h2 = 0; h2 < HID; h2++) y2 += y[h2] * ldsrow(wfS + h2 * HID);
    f32x16 z = ldsrow(btS);
    #pragma unroll
    for (int h2 = 0; h2 < HID; h2++) {
        float v = o1[h2] - ftanh(y2[h2]);
        z += v * ldsrow(wtS + h2 * HID);
    }
    return z;
}

// ---------------- NL eval (single-step LSTM cell + tanh + linear) -------------
__device__ __forceinline__ f32x16 nl_eval(f32x16 x,
                                          const float* __restrict__ WiT,
                                          const float* __restrict__ WgT,
                                          const float* __restrict__ WoT,
                                          const float* __restrict__ w2S,
                                          const float* __restrict__ bS) {
    f32x16 acc = 0.f;
    for (int j = 0; j < LH; j++) {
        f32x16 wi = ldsrow(WiT + j * HID);
        f32x16 wg = ldsrow(WgT + j * HID);
        f32x16 wo = ldsrow(WoT + j * HID);
        float gi = bS[j], gg = bS[2 * LH + j], go = bS[3 * LH + j];
        #pragma unroll
        for (int h = 0; h < HID; h++) {
            gi = fmaf(x[h], wi[h], gi);
            gg = fmaf(x[h], wg[h], gg);
            go = fmaf(x[h], wo[h], go);
        }
        float c = sigmoidf(gi) * ftanh(gg);
        float hh = sigmoidf(go) * ftanh(c);
        float th = ftanh(hh);
        acc += th * ldsrow(w2S + j * HID);
    }
    return acc;
}

// ---------------- fused chain: init + 10x GL + cstep + 10x NL ----------------
__global__ __launch_bounds__(NT, 2) void k_chain(
    const float* __restrict__ flow,
    const float* __restrict__ polys,
    const float* __restrict__ cheb_w, const float* __restrict__ cheb_b,
    const float* __restrict__ cou_w,
    const float* __restrict__ gl_wo, const float* __restrict__ gl_wf,
    const float* __restrict__ gl_wt, const float* __restrict__ gl_bt,
    const float* __restrict__ Wih, const float* __restrict__ bih,
    const float* __restrict__ w2,
    const float* __restrict__ c_w, const float* __restrict__ c_b,
    const float* __restrict__ c1_w, const float* __restrict__ c1_b,
    float* __restrict__ out) {
    __shared__ __align__(64) float buf[NT * HID];     // D rows (stride 16); also x staging
    __shared__ __align__(64) float woS[256], wfS[256], wtS[256];
    __shared__ __align__(64) float cwS[256], c1wS[256];
    __shared__ __align__(64) float WiT[LH * HID], WgT[LH * HID], WoT[LH * HID], w2S[LH * HID];
    __shared__ __align__(64) float chebS[KORD * CIN * HID], couS[CIN * HID];
    __shared__ __align__(64) float btS[16], cbS[16], c1bS[16], chebBS[16];
    __shared__ float bS[4 * LH];

    const int t = threadIdx.x;
    const int n = t;
    const int b = blockIdx.x;
    const float* L = polys + N * N;

    for (int i = t; i < 256; i += NT) {
        woS[i] = gl_wo[i]; wfS[i] = gl_wf[i]; wtS[i] = gl_wt[i];
        cwS[i] = c_w[i]; c1wS[i] = c1_w[i];
    }
    for (int i = t; i < LH * HID; i += NT) {
        int j = i >> 4, h = i & 15;
        WiT[i] = Wih[h * 4 * LH + j];
        WgT[i] = Wih[h * 4 * LH + 2 * LH + j];
        WoT[i] = Wih[h * 4 * LH + 3 * LH + j];
        w2S[i] = w2[i];
    }
    for (int i = t; i < 4 * LH; i += NT) bS[i] = bih[i];
    for (int i = t; i < KORD * CIN * HID; i += NT) chebS[i] = cheb_w[i];
    for (int i = t; i < HID; i += NT) {
        btS[i] = gl_bt[i]; cbS[i] = c_b[i]; c1bS[i] = c1_b[i]; chebBS[i] = cheb_b[i];
    }
    for (int i = t; i < CIN * HID; i += NT) couS[i] = cou_w[i];
    // stage x into buf (stride 8 per node)
    for (int i = t; i < N * CIN; i += NT) {
        int nn = i / CIN, c = i - nn * CIN;
        buf[nn * 8 + c] = flow[(size_t)b * N * CIN + i];
    }
    __syncthreads();

    // ---- init: prev2 = x@cou_w ; cur = chebyshev output ----
    f32x16 prev2 = 0.f, cur = 0.f;
    {
        float xv[CIN];
        #pragma unroll
        for (int c = 0; c < CIN; c++) xv[c] = (n < N) ? buf[n * 8 + c] : 0.f;
        #pragma unroll
        for (int c = 0; c < CIN; c++) prev2 += xv[c] * ldsrow(couS + c * HID);
        cur = ldsrow(chebBS);
        #pragma unroll 1
        for (int k = 0; k < KORD; k++) {
            const float* P = polys + (size_t)k * N * N + n;  // symmetric: col n == row n
            float hk0 = 0.f, hk1 = 0.f, hk2 = 0.f, hk3 = 0.f, hk4 = 0.f;
            #pragma unroll 4
            for (int m = 0; m < N; m++) {
                float p = P[(size_t)m * N];
                hk0 = fmaf(p, buf[m * 8 + 0], hk0);
                hk1 = fmaf(p, buf[m * 8 + 1], hk1);
                hk2 = fmaf(p, buf[m * 8 + 2], hk2);
                hk3 = fmaf(p, buf[m * 8 + 3], hk3);
                hk4 = fmaf(p, buf[m * 8 + 4], hk4);
            }
            cur += hk0 * ldsrow(chebS + (k * CIN + 0) * HID);
            cur += hk1 * ldsrow(chebS + (k * CIN + 1) * HID);
            cur += hk2 * ldsrow(chebS + (k * CIN + 2) * HID);
            cur += hk3 * ldsrow(chebS + (k * CIN + 3) * HID);
            cur += hk4 * ldsrow(chebS + (k * CIN + 4) * HID);
        }
    }

    const float* Lcol = L + n;
    // ---- GL chain ----
    for (int it = 0; it < 10; it++) {
        __syncthreads();                         // previous eval's readers done
        *(f32x16*)(buf + n * HID) = (n < N) ? cur : (f32x16)0.f;
        __syncthreads();
        f32x16 tt = gl_eval(Lcol, buf, cur, woS, wfS, wtS, btS);
        f32x16 tmp = prev2 + 2.f * tt;
        __syncthreads();
        *(f32x16*)(buf + n * HID) = (n < N) ? tmp : (f32x16)0.f;
        __syncthreads();
        f32x16 uu = gl_eval(Lcol, buf, tmp, woS, wfS, wtS, btS);
        f32x16 nc = cur + 0.5f * (tt + uu);
        prev2 = cur;
        cur = nc;
    }

    // ---- cstep + NL chain (pointwise; no barriers) ----
    if (n < N) {
        f32x16 s00 = ldsrow(cbS), s11 = ldsrow(c1bS);
        #pragma unroll
        for (int h2 = 0; h2 < HID; h2++) {
            s00 += prev2[h2] * ldsrow(cwS + h2 * HID);
            s11 += cur[h2] * ldsrow(c1wS + h2 * HID);
        }
        float* obase = out + ((size_t)b * N + n) * 10 * HID;
        f32x16 tt = nl_eval(s11, WiT, WgT, WoT, w2S, bS);
        f32x16 uu = nl_eval(s00 + 2.f * tt, WiT, WgT, WoT, w2S, bS);
        f32x16 g = cur + 0.5f * (tt + uu);
        f32x16 p2 = s11;
        *(f32x16*)obase = g;
        for (int i = 1; i < 10; i++) {
            tt = nl_eval(g, WiT, WgT, WoT, w2S, bS);
            uu = nl_eval(p2 + 2.f * tt, WiT, WgT, WoT, w2S, bS);
            f32x16 ng = g + 0.5f * (tt + uu);
            p2 = g;
            g = ng;
            *(f32x16*)(obase + i * HID) = g;
        }
    }
}

extern "C" void kernel_launch(void* const* d_in, const int* in_sizes, int n_in,
                              void* d_out, int out_size, void* d_ws, size_t ws_size,
                              hipStream_t stream) {
    const float* flow   = (const float*)d_in[0];
    const float* emb    = (const float*)d_in[1];
    const float* cheb_w = (const float*)d_in[2];
    const float* cheb_b = (const float*)d_in[3];
    const float* cou_w  = (const float*)d_in[4];
    const float* gl_out = (const float*)d_in[5];
    const float* gl_fk  = (const float*)d_in[6];
    const float* gl_tzw = (const float*)d_in[7];
    const float* gl_tzb = (const float*)d_in[8];
    const float* Wih    = (const float*)d_in[9];
    const float* lb     = (const float*)d_in[10];
    const float* w2     = (const float*)d_in[11];
    const float* c_w    = (const float*)d_in[12];
    const float* c_b    = (const float*)d_in[13];
    const float* c1_w   = (const float*)d_in[14];
    const float* c1_b   = (const float*)d_in[15];
    float* out = (float*)d_out;
    float* ws  = (float*)d_ws;

    size_t off = 0;
    float* polys = ws;       off += (size_t)KORD * N * N; off = (off + 255) & ~(size_t)255;
    float* G     = ws + off; off += (size_t)N * N;        off = (off + 255) & ~(size_t)255;
    float* dinv  = ws + off; off += 512;

    k_cosine<<<N, NT, 0, stream>>>(emb, G, dinv);
    k_laplacian<<<N, NT, 0, stream>>>(G, dinv, polys);
    for (int k = 2; k < KORD; k++)
        k_cheb_step<<<N, NT, 0, stream>>>(polys, k);
    k_chain<<<BATCH, NT, 0, stream>>>(flow, polys, cheb_w, cheb_b, cou_w,
                                      gl_out, gl_fk, gl_tzw, gl_tzb,
                                      Wih, lb, w2, c_w, c_b, c1_w, c1_b, out);
}